// Round 13
// baseline (119.360 us; speedup 1.0000x reference)
//
#include <hip/hip_runtime.h>
#include <stdint.h>

typedef float f4 __attribute__((ext_vector_type(4)));
typedef __attribute__((ext_vector_type(4))) float f32x4;
typedef __attribute__((ext_vector_type(8))) short bf16x8;

#define NV 65536       // total vectors (16*4096)
#define D 64           // embedding dim
#define K 1024         // codebook size
#define BM 64          // vectors per block (2 waves x 32)
#define NT 128         // threads per block
#define TILE 128       // codes per tile (8 tiles)
#define NPH 16         // 2 passes x 8 tiles
#define MARGIN 4.0e-3f // r8/r12-validated sound margin (exact A*)
#define CAP 32
#define LOSS_OFF 4194304
#define IDX_OFF  4194305

__device__ __forceinline__ unsigned f2bf(float f) {  // RNE fp32->bf16
  unsigned u = __builtin_bit_cast(unsigned, f);
  return (u + 0x7fffu + ((u >> 16) & 1u)) >> 16;
}

// Prep: thread n = one code row.  (1) numpy-exact eSq (pairwise-8, separate
// mul/add rounding); (2) bf16 row pre-swizzled exactly as the LDS layout:
// 16B chunk c -> blob[n*128 + ((c*16) ^ ((n&7)<<4))].  Main-kernel staging
// is then a LINEAR global->LDS copy (rule: swizzle the source, keep LDS dest
// linear for global_load_lds).
__global__ void vq_prep(const float* __restrict__ E, float* __restrict__ ws,
                        float* __restrict__ loss) {
  const int n = blockIdx.x * 256 + threadIdx.x;   // 0..1023
  if (n == 0) *loss = 0.0f;
  if (n >= K) return;
  const float* row = E + (size_t)n * D;
  float r[8];
#pragma unroll
  for (int j = 0; j < 8; ++j) r[j] = __fmul_rn(row[j], row[j]);
#pragma unroll
  for (int i = 8; i < D; i += 8)
#pragma unroll
    for (int j = 0; j < 8; ++j)
      r[j] = __fadd_rn(r[j], __fmul_rn(row[i + j], row[i + j]));
  ws[n] = __fadd_rn(
      __fadd_rn(__fadd_rn(r[0], r[1]), __fadd_rn(r[2], r[3])),
      __fadd_rn(__fadd_rn(r[4], r[5]), __fadd_rn(r[6], r[7])));

  char* blob = reinterpret_cast<char*>(ws + K);
  const int sw = (n & 7) << 4;
#pragma unroll
  for (int c = 0; c < 8; ++c) {
    f4 a = *reinterpret_cast<const f4*>(row + c * 8);
    f4 b = *reinterpret_cast<const f4*>(row + c * 8 + 4);
    uint4 pk;
    pk.x = f2bf(a[0]) | (f2bf(a[1]) << 16);
    pk.y = f2bf(a[2]) | (f2bf(a[3]) << 16);
    pk.z = f2bf(b[0]) | (f2bf(b[1]) << 16);
    pk.w = f2bf(b[2]) | (f2bf(b[3]) << 16);
    *reinterpret_cast<uint4*>(blob + n * 128 + ((c * 16) ^ sw)) = pk;
  }
}

__device__ __forceinline__ bf16x8 ld_a(const float* p) {
  f4 a = *reinterpret_cast<const f4*>(p);
  f4 b = *reinterpret_cast<const f4*>(p + 4);
  bf16x8 r;
  r[0] = (short)f2bf(a[0]); r[1] = (short)f2bf(a[1]);
  r[2] = (short)f2bf(a[2]); r[3] = (short)f2bf(a[3]);
  r[4] = (short)f2bf(b[0]); r[5] = (short)f2bf(b[1]);
  r[6] = (short)f2bf(b[2]); r[7] = (short)f2bf(b[3]);
  return r;
}

// async global->LDS, 16 B per lane (CK-style addrspace casts)
__device__ __forceinline__ void gload_lds16(const void* g, void* l) {
  auto gp = (const __attribute__((address_space(1))) unsigned int*)(uintptr_t)g;
  auto lp = (__attribute__((address_space(3))) unsigned int*)(uintptr_t)l;
  __builtin_amdgcn_global_load_lds(gp, lp, 16, 0, 0);
}

// Two-pass MFMA filter with m97-style pipelined staging: pre-swizzled bf16
// codebook blob -> double-buffered LDS tiles via async global_load_lds,
// ONE barrier per phase.  Pass 1 (phases 0-7): exact bf16-score min A*.
// Pass 2 (phases 8-15): collect u <= A*+M.  Exact fp32 rescore of candidates
// (reference-exact chain; indices bit-identical to all passing rounds).
__global__ __launch_bounds__(NT, 2) void vq_main(
    const float* __restrict__ X, const float* __restrict__ E,
    const float* __restrict__ ws, float* __restrict__ out) {
  __shared__ unsigned short EbfL[2][TILE * 64];  // 2 x 16 KB, swizzled layout
  __shared__ float eSqL[K];                      // 4 KB
  __shared__ unsigned cntL[BM];
  __shared__ unsigned short candL[BM * CAP];     // 4 KB
  __shared__ int sidxL[BM];

  const float* eSq = ws;
  const char* blob = reinterpret_cast<const char*>(ws + K);

  const int t = threadIdx.x;
  const int lane = t & 63;
  const int w = t >> 6;                          // 0..1
  const int l15 = lane & 15, l4 = lane >> 4;
  const int bv0 = blockIdx.x * BM;

  // A-fragments: wave w owns 32 vectors (2 row-tiles), bf16 in registers.
  const float* xv0 = X + (size_t)(bv0 + w * 32 + l15) * D;
  const float* xv1 = xv0 + 16 * D;
  bf16x8 a00 = ld_a(xv0 + l4 * 8);
  bf16x8 a01 = ld_a(xv0 + 32 + l4 * 8);
  bf16x8 a10 = ld_a(xv1 + l4 * 8);
  bf16x8 a11 = ld_a(xv1 + 32 + l4 * 8);

#pragma unroll
  for (int i = 0; i < 8; ++i) eSqL[t + NT * i] = eSq[t + NT * i];
  if (t < BM) cntL[t] = 0;

  // prologue: stage tile 0 -> buf 0 (each wave copies 8 KB linearly)
  {
    const char* src = blob + w * 8192 + lane * 16;
    char* dst = reinterpret_cast<char*>(&EbfL[0][0]) + w * 8192;
#pragma unroll
    for (int i = 0; i < 8; ++i) gload_lds16(src + i * 1024, dst + i * 1024);
  }
  __syncthreads();

  float umin[8];
#pragma unroll
  for (int i = 0; i < 8; ++i) umin[i] = 3.4e38f;
  float thr[8];

#pragma unroll 1
  for (int p = 0; p < NPH; ++p) {
    // issue next tile's async loads BEFORE compute (latency hides under MFMA)
    if (p < NPH - 1) {
      const int tn = (p + 1) & 7;
      const char* src = blob + tn * 16384 + w * 8192 + lane * 16;
      char* dst = reinterpret_cast<char*>(&EbfL[(p + 1) & 1][0]) + w * 8192;
#pragma unroll
      for (int i = 0; i < 8; ++i) gload_lds16(src + i * 1024, dst + i * 1024);
    }
    const char* eB = reinterpret_cast<const char*>(&EbfL[p & 1][0]);
    const int tb = p & 7;
    if (p < 8) {
      // ---- pass 1: per-vector min of u = fl(ee - 2*m~) ----
#pragma unroll
      for (int ct = 0; ct < 8; ++ct) {
        const int lr = ct * 16 + l15;
        const int rsw = (lr & 7) << 4;
        bf16x8 b0 = *reinterpret_cast<const bf16x8*>(eB + lr * 128 + ((l4 * 16) ^ rsw));
        bf16x8 b1 = *reinterpret_cast<const bf16x8*>(eB + lr * 128 + ((64 + l4 * 16) ^ rsw));
        f32x4 acc0 = {0.f, 0.f, 0.f, 0.f}, acc1 = {0.f, 0.f, 0.f, 0.f};
        acc0 = __builtin_amdgcn_mfma_f32_16x16x32_bf16(a00, b0, acc0, 0, 0, 0);
        acc0 = __builtin_amdgcn_mfma_f32_16x16x32_bf16(a01, b1, acc0, 0, 0, 0);
        acc1 = __builtin_amdgcn_mfma_f32_16x16x32_bf16(a10, b0, acc1, 0, 0, 0);
        acc1 = __builtin_amdgcn_mfma_f32_16x16x32_bf16(a11, b1, acc1, 0, 0, 0);
        const float ee = eSqL[tb * TILE + lr];
#pragma unroll
        for (int r = 0; r < 4; ++r) {
          umin[r]     = fminf(umin[r],     __fmaf_rn(-2.0f, acc0[r], ee));
          umin[4 + r] = fminf(umin[4 + r], __fmaf_rn(-2.0f, acc1[r], ee));
        }
      }
      if (p == 7) {  // exact A* across the 16 column-lanes -> frozen threshold
#pragma unroll
        for (int i = 0; i < 8; ++i) {
#pragma unroll
          for (int off = 1; off < 16; off <<= 1)
            umin[i] = fminf(umin[i], __shfl_xor(umin[i], off, 64));
          thr[i] = umin[i] + MARGIN;
        }
      }
    } else {
      // ---- pass 2: collect candidates (u <= A* + M) ----
#pragma unroll
      for (int ct = 0; ct < 8; ++ct) {
        const int lr = ct * 16 + l15;
        const int rsw = (lr & 7) << 4;
        bf16x8 b0 = *reinterpret_cast<const bf16x8*>(eB + lr * 128 + ((l4 * 16) ^ rsw));
        bf16x8 b1 = *reinterpret_cast<const bf16x8*>(eB + lr * 128 + ((64 + l4 * 16) ^ rsw));
        f32x4 acc0 = {0.f, 0.f, 0.f, 0.f}, acc1 = {0.f, 0.f, 0.f, 0.f};
        acc0 = __builtin_amdgcn_mfma_f32_16x16x32_bf16(a00, b0, acc0, 0, 0, 0);
        acc0 = __builtin_amdgcn_mfma_f32_16x16x32_bf16(a01, b1, acc0, 0, 0, 0);
        acc1 = __builtin_amdgcn_mfma_f32_16x16x32_bf16(a10, b0, acc1, 0, 0, 0);
        acc1 = __builtin_amdgcn_mfma_f32_16x16x32_bf16(a11, b1, acc1, 0, 0, 0);
        const int gc = tb * TILE + lr;
        const float ee = eSqL[gc];
#pragma unroll
        for (int r = 0; r < 4; ++r) {
          if (__fmaf_rn(-2.0f, acc0[r], ee) <= thr[r]) {
            const int v = w * 32 + l4 * 4 + r;
            const unsigned pos = atomicAdd(&cntL[v], 1u);
            if (pos < CAP) candL[v * CAP + pos] = (unsigned short)gc;
          }
          if (__fmaf_rn(-2.0f, acc1[r], ee) <= thr[4 + r]) {
            const int v = w * 32 + 16 + l4 * 4 + r;
            const unsigned pos = atomicAdd(&cntL[v], 1u);
            if (pos < CAP) candL[v * CAP + pos] = (unsigned short)gc;
          }
        }
      }
    }
    __syncthreads();
  }

  // ====== exact fp32 rescore (bit-identical chain to passing rounds) ======
  {
    const int v = t >> 1, par = t & 1;
    const int gv = bv0 + v;
    const float* xr = X + (size_t)gv * D;
    float rr[8];
#pragma unroll
    for (int j = 0; j < 8; ++j) rr[j] = __fmul_rn(xr[j], xr[j]);
#pragma unroll
    for (int i = 8; i < 64; i += 8)
#pragma unroll
      for (int j = 0; j < 8; ++j)
        rr[j] = __fadd_rn(rr[j], __fmul_rn(xr[i + j], xr[i + j]));
    const float xx = __fadd_rn(
        __fadd_rn(__fadd_rn(rr[0], rr[1]), __fadd_rn(rr[2], rr[3])),
        __fadd_rn(__fadd_rn(rr[4], rr[5]), __fadd_rn(rr[6], rr[7])));

    float best = 3.4e38f;
    int bi = 0x7fffffff;
    const unsigned n = cntL[v];
    if (n <= CAP) {
      for (unsigned i = par; i < n; i += 2) {
        const int c = candL[v * CAP + i];
        const float* er = E + (size_t)c * D;
        float m = 0.f;
#pragma unroll
        for (int j = 0; j < 64; ++j) m = fmaf(er[j], xr[j], m);
        const float dd = __fsub_rn(__fadd_rn(xx, eSqL[c]), 2.0f * m);
        if (dd < best || (dd == best && c < bi)) { best = dd; bi = c; }
      }
    } else {  // overflow fallback: exact full scan (deterministic, correct)
      for (int c = par; c < K; c += 2) {
        const float* er = E + (size_t)c * D;
        float m = 0.f;
#pragma unroll
        for (int j = 0; j < 64; ++j) m = fmaf(er[j], xr[j], m);
        const float dd = __fsub_rn(__fadd_rn(xx, eSqL[c]), 2.0f * m);
        if (dd < best || (dd == best && c < bi)) { best = dd; bi = c; }
      }
    }
    const float ov = __shfl_xor(best, 1, 64);
    const int oi = __shfl_xor(bi, 1, 64);
    if (ov < best || (ov == best && oi < bi)) { best = ov; bi = oi; }
    if (par == 0) sidxL[v] = bi;
  }
  __syncthreads();

  // ============== epilogue: quantized out, indices, loss ==================
  {
    const int v = t >> 1, h = t & 1;
    const int gv = bv0 + v;
    const int code = sidxL[v];
    const f4* er = reinterpret_cast<const f4*>(E + (size_t)code * D + h * 32);
    const f4* xr = reinterpret_cast<const f4*>(X + (size_t)gv * D + h * 32);
    f4* op = reinterpret_cast<f4*>(out + (size_t)gv * D + h * 32);
    float lsum = 0.f;
#pragma unroll
    for (int i = 0; i < 8; ++i) {
      f4 e4 = er[i], x4 = xr[i];
      float d0 = e4[0] - x4[0], d1 = e4[1] - x4[1];
      float d2 = e4[2] - x4[2], d3 = e4[3] - x4[3];
      lsum += d0 * d0 + d1 * d1 + d2 * d2 + d3 * d3;
      op[i] = e4;
    }
    if (t < BM) out[IDX_OFF + bv0 + t] = (float)sidxL[t];
#pragma unroll
    for (int off = 1; off < 64; off <<= 1) lsum += __shfl_xor(lsum, off, 64);
    if (lane == 0)
      atomicAdd(out + LOSS_OFF, lsum * (1.25f / (float)(NV * (size_t)D)));
  }
}

extern "C" void kernel_launch(void* const* d_in, const int* in_sizes, int n_in,
                              void* d_out, int out_size, void* d_ws, size_t ws_size,
                              hipStream_t stream) {
  const float* X = (const float*)d_in[0];
  const float* E = (const float*)d_in[1];
  float* out = (float*)d_out;
  float* ws = (float*)d_ws;  // [0..1024): eSq; then 128 KB swizzled bf16 blob
  vq_prep<<<4, 256, 0, stream>>>(E, ws, out + LOSS_OFF);
  vq_main<<<NV / BM, NT, 0, stream>>>(X, E, ws, out);
}

// Round 14
// 105.824 us; speedup vs baseline: 1.1279x; 1.1279x over previous
//
#include <hip/hip_runtime.h>

typedef float f4 __attribute__((ext_vector_type(4)));
typedef __attribute__((ext_vector_type(4))) float f32x4;
typedef __attribute__((ext_vector_type(8))) short bf16x8;

#define NV 65536       // total vectors (16*4096)
#define D 64           // embedding dim
#define K 1024         // codebook size
#define BM 64          // vectors per block (4 waves x 16)
#define MARGIN 4.0e-3f // r8/r12-validated sound margin (with exact A*)
#define CAP 32
#define LOSS_OFF 4194304
#define IDX_OFF  4194305

__device__ __forceinline__ unsigned f2bf(float f) {  // RNE fp32->bf16
  unsigned u = __builtin_bit_cast(unsigned, f);
  return (u + 0x7fffu + ((u >> 16) & 1u)) >> 16;
}

// Prep (r11-proven): (1) numpy-exact eSq; (2) loss zero; (3) E -> bf16 blob
// in MFMA B-fragment layout: slot n = fi*64+lane, fi = ct*2+half; lane gets
// Ebf16[ct*16+(lane&15)][half*32+(lane>>4)*8 ..+8).  32 blocks x 256 thr.
__global__ void vq_prep(const float* __restrict__ E, float* __restrict__ ws,
                        float* __restrict__ loss) {
  const int n = blockIdx.x * 256 + threadIdx.x;   // 0..8191
  unsigned short* Ebf = reinterpret_cast<unsigned short*>(ws + K);
  if (n == 0) *loss = 0.0f;
  if (n < K) {
    const float* row = E + (size_t)n * D;
    float r[8];
#pragma unroll
    for (int j = 0; j < 8; ++j) r[j] = __fmul_rn(row[j], row[j]);
#pragma unroll
    for (int i = 8; i < D; i += 8)
#pragma unroll
      for (int j = 0; j < 8; ++j)
        r[j] = __fadd_rn(r[j], __fmul_rn(row[i + j], row[i + j]));
    ws[n] = __fadd_rn(
        __fadd_rn(__fadd_rn(r[0], r[1]), __fadd_rn(r[2], r[3])),
        __fadd_rn(__fadd_rn(r[4], r[5]), __fadd_rn(r[6], r[7])));
  }
  const int fi = n >> 6, lane = n & 63;
  const int ct = fi >> 1, half = fi & 1;
  const int code = ct * 16 + (lane & 15);
  const int d0 = half * 32 + (lane >> 4) * 8;
  const float* src = E + (size_t)code * D + d0;
  f4 a = *reinterpret_cast<const f4*>(src);
  f4 b = *reinterpret_cast<const f4*>(src + 4);
  uint4 pk;
  pk.x = f2bf(a[0]) | (f2bf(a[1]) << 16);
  pk.y = f2bf(a[2]) | (f2bf(a[3]) << 16);
  pk.z = f2bf(b[0]) | (f2bf(b[1]) << 16);
  pk.w = f2bf(b[2]) | (f2bf(b[3]) << 16);
  *reinterpret_cast<uint4*>(Ebf + (size_t)n * 8) = pk;
}

__device__ __forceinline__ bf16x8 ld_a(const float* p) {
  f4 a = *reinterpret_cast<const f4*>(p);
  f4 b = *reinterpret_cast<const f4*>(p + 4);
  bf16x8 r;
  r[0] = (short)f2bf(a[0]); r[1] = (short)f2bf(a[1]);
  r[2] = (short)f2bf(a[2]); r[3] = (short)f2bf(a[3]);
  r[4] = (short)f2bf(b[0]); r[5] = (short)f2bf(b[1]);
  r[6] = (short)f2bf(b[2]); r[7] = (short)f2bf(b[3]);
  return r;
}

// Barrier-free two-pass MFMA filter: B-frags streamed from the L2-resident
// pre-swizzled blob (r11's load path), r8's cheap op mix (fmin / cmp only).
// Pass 1: exact per-vector A* of u = fl(ee - 2*m~).  Pass 2: re-stream,
// collect u <= A*+M.  Exact fp32 rescore (reference-exact chain).
__global__ __launch_bounds__(256, 2) void vq_main(
    const float* __restrict__ X, const float* __restrict__ E,
    const float* __restrict__ ws, float* __restrict__ out) {
  __shared__ float eSqL[K];                  // 4 KB
  __shared__ unsigned cntL[BM];
  __shared__ unsigned short candL[BM * CAP]; // 4 KB
  __shared__ int sidxL[BM];

  const unsigned short* Ebf = reinterpret_cast<const unsigned short*>(ws + K);

  const int t = threadIdx.x;
  const int lane = t & 63;
  const int w = t >> 6;                      // 4 waves x 16 vectors
  const int l15 = lane & 15, l4 = lane >> 4;
  const int bv0 = blockIdx.x * BM;

  // A-fragments from global X (L2-hot), bf16 in registers (r9/r11-proven).
  const float* xv = X + (size_t)(bv0 + w * 16 + l15) * D;
  bf16x8 a0 = ld_a(xv + l4 * 8);
  bf16x8 a1 = ld_a(xv + 32 + l4 * 8);

#pragma unroll
  for (int i = 0; i < 4; ++i) eSqL[t + 256 * i] = ws[t + 256 * i];
  if (t < BM) cntL[t] = 0;
  __syncthreads();   // eSqL + cntL visible; no further barriers until rescore

  const unsigned short* ebase = Ebf + (size_t)lane * 8;

  // ================= PASS 1: exact per-vector min of u ====================
  float umin[4];
#pragma unroll
  for (int r = 0; r < 4; ++r) umin[r] = 3.4e38f;
#pragma unroll 4
  for (int ct = 0; ct < 64; ++ct) {
    bf16x8 b0 = *reinterpret_cast<const bf16x8*>(ebase + ct * 1024);
    bf16x8 b1 = *reinterpret_cast<const bf16x8*>(ebase + ct * 1024 + 512);
    f32x4 acc = {0.f, 0.f, 0.f, 0.f};
    acc = __builtin_amdgcn_mfma_f32_16x16x32_bf16(a0, b0, acc, 0, 0, 0);
    acc = __builtin_amdgcn_mfma_f32_16x16x32_bf16(a1, b1, acc, 0, 0, 0);
    const float ee = eSqL[ct * 16 + l15];
#pragma unroll
    for (int r = 0; r < 4; ++r)
      umin[r] = fminf(umin[r], __fmaf_rn(-2.0f, acc[r], ee));
  }
  // cross-lane (16-group) min -> exact A*, frozen sound threshold
  float thr[4];
#pragma unroll
  for (int r = 0; r < 4; ++r) {
#pragma unroll
    for (int off = 1; off < 16; off <<= 1)
      umin[r] = fminf(umin[r], __shfl_xor(umin[r], off, 64));
    thr[r] = umin[r] + MARGIN;
  }

  // ================= PASS 2: collect candidates (u <= A* + M) =============
#pragma unroll 4
  for (int ct = 0; ct < 64; ++ct) {
    bf16x8 b0 = *reinterpret_cast<const bf16x8*>(ebase + ct * 1024);
    bf16x8 b1 = *reinterpret_cast<const bf16x8*>(ebase + ct * 1024 + 512);
    f32x4 acc = {0.f, 0.f, 0.f, 0.f};
    acc = __builtin_amdgcn_mfma_f32_16x16x32_bf16(a0, b0, acc, 0, 0, 0);
    acc = __builtin_amdgcn_mfma_f32_16x16x32_bf16(a1, b1, acc, 0, 0, 0);
    const int gc = ct * 16 + l15;
    const float ee = eSqL[gc];
#pragma unroll
    for (int r = 0; r < 4; ++r) {
      if (__fmaf_rn(-2.0f, acc[r], ee) <= thr[r]) {
        const int v = w * 16 + l4 * 4 + r;
        const unsigned pos = atomicAdd(&cntL[v], 1u);
        if (pos < CAP) candL[v * CAP + pos] = (unsigned short)gc;
      }
    }
  }
  __syncthreads();

  // ====== exact fp32 rescore (bit-identical chain to passing rounds) ======
  {
    const int v = t >> 2, par = t & 3;
    const int gv = bv0 + v;
    const float* xr = X + (size_t)gv * D;
    float rr[8];
#pragma unroll
    for (int j = 0; j < 8; ++j) rr[j] = __fmul_rn(xr[j], xr[j]);
#pragma unroll
    for (int i = 8; i < 64; i += 8)
#pragma unroll
      for (int j = 0; j < 8; ++j)
        rr[j] = __fadd_rn(rr[j], __fmul_rn(xr[i + j], xr[i + j]));
    const float xx = __fadd_rn(
        __fadd_rn(__fadd_rn(rr[0], rr[1]), __fadd_rn(rr[2], rr[3])),
        __fadd_rn(__fadd_rn(rr[4], rr[5]), __fadd_rn(rr[6], rr[7])));

    float best = 3.4e38f;
    int bi = 0x7fffffff;
    const unsigned n = cntL[v];
    if (n <= CAP) {
      for (unsigned i = par; i < n; i += 4) {
        const int c = candL[v * CAP + i];
        const float* er = E + (size_t)c * D;
        float m = 0.f;
#pragma unroll
        for (int j = 0; j < 64; ++j) m = fmaf(er[j], xr[j], m);
        const float dd = __fsub_rn(__fadd_rn(xx, eSqL[c]), 2.0f * m);
        if (dd < best || (dd == best && c < bi)) { best = dd; bi = c; }
      }
    } else {  // overflow fallback: exact full scan (deterministic, correct)
      for (int c = par; c < K; c += 4) {
        const float* er = E + (size_t)c * D;
        float m = 0.f;
#pragma unroll
        for (int j = 0; j < 64; ++j) m = fmaf(er[j], xr[j], m);
        const float dd = __fsub_rn(__fadd_rn(xx, eSqL[c]), 2.0f * m);
        if (dd < best || (dd == best && c < bi)) { best = dd; bi = c; }
      }
    }
#pragma unroll
    for (int off = 1; off < 4; off <<= 1) {
      const float ov = __shfl_xor(best, off, 64);
      const int oi = __shfl_xor(bi, off, 64);
      if (ov < best || (ov == best && oi < bi)) { best = ov; bi = oi; }
    }
    if (par == 0) sidxL[v] = bi;
  }
  __syncthreads();

  // ============== epilogue: quantized out, indices, loss ==================
  {
    const int v = t >> 2, h = t & 3;
    const int gv = bv0 + v;
    const int code = sidxL[v];
    const f4* er = reinterpret_cast<const f4*>(E + (size_t)code * D + h * 16);
    const f4* xr = reinterpret_cast<const f4*>(X + (size_t)gv * D + h * 16);
    f4* op = reinterpret_cast<f4*>(out + (size_t)gv * D + h * 16);
    float lsum = 0.f;
#pragma unroll
    for (int i = 0; i < 4; ++i) {
      f4 e4 = er[i], x4 = xr[i];
      float d0 = e4[0] - x4[0], d1 = e4[1] - x4[1];
      float d2 = e4[2] - x4[2], d3 = e4[3] - x4[3];
      lsum += d0 * d0 + d1 * d1 + d2 * d2 + d3 * d3;
      op[i] = e4;
    }
    if (t < BM) out[IDX_OFF + bv0 + t] = (float)sidxL[t];
#pragma unroll
    for (int off = 1; off < 64; off <<= 1) lsum += __shfl_xor(lsum, off, 64);
    if (lane == 0)
      atomicAdd(out + LOSS_OFF, lsum * (1.25f / (float)(NV * (size_t)D)));
  }
}

extern "C" void kernel_launch(void* const* d_in, const int* in_sizes, int n_in,
                              void* d_out, int out_size, void* d_ws, size_t ws_size,
                              hipStream_t stream) {
  const float* X = (const float*)d_in[0];
  const float* E = (const float*)d_in[1];
  float* out = (float*)d_out;
  float* ws = (float*)d_ws;  // [0..1024): eSq; then 128 KB swizzled bf16 blob
  vq_prep<<<32, 256, 0, stream>>>(E, ws, out + LOSS_OFF);
  vq_main<<<NV / BM, 256, 0, stream>>>(X, E, ws, out);
}

// Round 15
// 98.447 us; speedup vs baseline: 1.2124x; 1.0749x over previous
//
#include <hip/hip_runtime.h>

typedef float f4 __attribute__((ext_vector_type(4)));
typedef __attribute__((ext_vector_type(4))) float f32x4;
typedef __attribute__((ext_vector_type(8))) short bf16x8;

#define NV 65536       // total vectors (16*4096)
#define D 64           // embedding dim
#define K 1024         // codebook size
#define NT 256         // threads (4 waves)
#define BM 128         // vectors per block (4 waves x 32)
#define MARGIN 4.0e-3f // r8/r12-validated sound margin (with exact A*)
#define CAP 32
#define LOSS_OFF 4194304
#define IDX_OFF  4194305

__device__ __forceinline__ unsigned f2bf(float f) {  // RNE fp32->bf16
  unsigned u = __builtin_bit_cast(unsigned, f);
  return (u + 0x7fffu + ((u >> 16) & 1u)) >> 16;
}

// Prep (r11/r14-proven): (1) numpy-exact eSq; (2) loss zero; (3) E -> bf16
// blob in MFMA B-fragment layout: slot n = fi*64+lane, fi = ct*2+half; lane
// gets Ebf16[ct*16+(lane&15)][half*32+(lane>>4)*8 ..+8).  32 blk x 256 thr.
__global__ void vq_prep(const float* __restrict__ E, float* __restrict__ ws,
                        float* __restrict__ loss) {
  const int n = blockIdx.x * 256 + threadIdx.x;   // 0..8191
  unsigned short* Ebf = reinterpret_cast<unsigned short*>(ws + K);
  if (n == 0) *loss = 0.0f;
  if (n < K) {
    const float* row = E + (size_t)n * D;
    float r[8];
#pragma unroll
    for (int j = 0; j < 8; ++j) r[j] = __fmul_rn(row[j], row[j]);
#pragma unroll
    for (int i = 8; i < D; i += 8)
#pragma unroll
      for (int j = 0; j < 8; ++j)
        r[j] = __fadd_rn(r[j], __fmul_rn(row[i + j], row[i + j]));
    ws[n] = __fadd_rn(
        __fadd_rn(__fadd_rn(r[0], r[1]), __fadd_rn(r[2], r[3])),
        __fadd_rn(__fadd_rn(r[4], r[5]), __fadd_rn(r[6], r[7])));
  }
  const int fi = n >> 6, lane = n & 63;
  const int ct = fi >> 1, half = fi & 1;
  const int code = ct * 16 + (lane & 15);
  const int d0 = half * 32 + (lane >> 4) * 8;
  const float* src = E + (size_t)code * D + d0;
  f4 a = *reinterpret_cast<const f4*>(src);
  f4 b = *reinterpret_cast<const f4*>(src + 4);
  uint4 pk;
  pk.x = f2bf(a[0]) | (f2bf(a[1]) << 16);
  pk.y = f2bf(a[2]) | (f2bf(a[3]) << 16);
  pk.z = f2bf(b[0]) | (f2bf(b[1]) << 16);
  pk.w = f2bf(b[2]) | (f2bf(b[3]) << 16);
  *reinterpret_cast<uint4*>(Ebf + (size_t)n * 8) = pk;
}

__device__ __forceinline__ bf16x8 ld_a(const float* p) {
  f4 a = *reinterpret_cast<const f4*>(p);
  f4 b = *reinterpret_cast<const f4*>(p + 4);
  bf16x8 r;
  r[0] = (short)f2bf(a[0]); r[1] = (short)f2bf(a[1]);
  r[2] = (short)f2bf(a[2]); r[3] = (short)f2bf(a[3]);
  r[4] = (short)f2bf(b[0]); r[5] = (short)f2bf(b[1]);
  r[6] = (short)f2bf(b[2]); r[7] = (short)f2bf(b[3]);
  return r;
}

// Barrier-free two-pass MFMA filter, 32 vectors/wave (2 row-tiles): halves
// wave count and L2 traffic vs r14; 4 MFMA per 2 loads.  Pass 1: exact
// per-vector A*.  Pass 2: re-stream, collect u <= A*+M.  Exact fp32 rescore.
__global__ __launch_bounds__(NT, 2) void vq_main(
    const float* __restrict__ X, const float* __restrict__ E,
    const float* __restrict__ ws, float* __restrict__ out) {
  __shared__ float eSqL[K];                  // 4 KB
  __shared__ unsigned cntL[BM];
  __shared__ unsigned short candL[BM * CAP]; // 8 KB
  __shared__ int sidxL[BM];

  const unsigned short* Ebf = reinterpret_cast<const unsigned short*>(ws + K);

  const int t = threadIdx.x;
  const int lane = t & 63;
  const int w = t >> 6;                      // 4 waves x 32 vectors
  const int l15 = lane & 15, l4 = lane >> 4;
  const int bv0 = blockIdx.x * BM;

  // A-fragments: wave w owns vectors w*32..w*32+31 (row-tiles 0,1).
  const float* xv0 = X + (size_t)(bv0 + w * 32 + l15) * D;
  const float* xv1 = xv0 + 16 * D;
  bf16x8 a00 = ld_a(xv0 + l4 * 8);
  bf16x8 a01 = ld_a(xv0 + 32 + l4 * 8);
  bf16x8 a10 = ld_a(xv1 + l4 * 8);
  bf16x8 a11 = ld_a(xv1 + 32 + l4 * 8);

#pragma unroll
  for (int i = 0; i < 4; ++i) eSqL[t + NT * i] = ws[t + NT * i];
  if (t < BM) cntL[t] = 0;
  __syncthreads();   // eSqL + cntL visible; no further barriers until rescore

  const unsigned short* ebase = Ebf + (size_t)lane * 8;

  // ================= PASS 1: exact per-vector min of u ====================
  float umin[8];
#pragma unroll
  for (int r = 0; r < 8; ++r) umin[r] = 3.4e38f;
#pragma unroll 8
  for (int ct = 0; ct < 64; ++ct) {
    bf16x8 b0 = *reinterpret_cast<const bf16x8*>(ebase + ct * 1024);
    bf16x8 b1 = *reinterpret_cast<const bf16x8*>(ebase + ct * 1024 + 512);
    f32x4 acc0 = {0.f, 0.f, 0.f, 0.f}, acc1 = {0.f, 0.f, 0.f, 0.f};
    acc0 = __builtin_amdgcn_mfma_f32_16x16x32_bf16(a00, b0, acc0, 0, 0, 0);
    acc0 = __builtin_amdgcn_mfma_f32_16x16x32_bf16(a01, b1, acc0, 0, 0, 0);
    acc1 = __builtin_amdgcn_mfma_f32_16x16x32_bf16(a10, b0, acc1, 0, 0, 0);
    acc1 = __builtin_amdgcn_mfma_f32_16x16x32_bf16(a11, b1, acc1, 0, 0, 0);
    const float ee = eSqL[ct * 16 + l15];
#pragma unroll
    for (int r = 0; r < 4; ++r) {
      umin[r]     = fminf(umin[r],     __fmaf_rn(-2.0f, acc0[r], ee));
      umin[4 + r] = fminf(umin[4 + r], __fmaf_rn(-2.0f, acc1[r], ee));
    }
  }
  // cross-lane (16-group) min -> exact A*, frozen sound threshold
  float thr[8];
#pragma unroll
  for (int r = 0; r < 8; ++r) {
#pragma unroll
    for (int off = 1; off < 16; off <<= 1)
      umin[r] = fminf(umin[r], __shfl_xor(umin[r], off, 64));
    thr[r] = umin[r] + MARGIN;
  }

  // ================= PASS 2: collect candidates (u <= A* + M) =============
#pragma unroll 8
  for (int ct = 0; ct < 64; ++ct) {
    bf16x8 b0 = *reinterpret_cast<const bf16x8*>(ebase + ct * 1024);
    bf16x8 b1 = *reinterpret_cast<const bf16x8*>(ebase + ct * 1024 + 512);
    f32x4 acc0 = {0.f, 0.f, 0.f, 0.f}, acc1 = {0.f, 0.f, 0.f, 0.f};
    acc0 = __builtin_amdgcn_mfma_f32_16x16x32_bf16(a00, b0, acc0, 0, 0, 0);
    acc0 = __builtin_amdgcn_mfma_f32_16x16x32_bf16(a01, b1, acc0, 0, 0, 0);
    acc1 = __builtin_amdgcn_mfma_f32_16x16x32_bf16(a10, b0, acc1, 0, 0, 0);
    acc1 = __builtin_amdgcn_mfma_f32_16x16x32_bf16(a11, b1, acc1, 0, 0, 0);
    const int gc = ct * 16 + l15;
    const float ee = eSqL[gc];
#pragma unroll
    for (int r = 0; r < 4; ++r) {
      if (__fmaf_rn(-2.0f, acc0[r], ee) <= thr[r]) {
        const int v = w * 32 + l4 * 4 + r;
        const unsigned pos = atomicAdd(&cntL[v], 1u);
        if (pos < CAP) candL[v * CAP + pos] = (unsigned short)gc;
      }
      if (__fmaf_rn(-2.0f, acc1[r], ee) <= thr[4 + r]) {
        const int v = w * 32 + 16 + l4 * 4 + r;
        const unsigned pos = atomicAdd(&cntL[v], 1u);
        if (pos < CAP) candL[v * CAP + pos] = (unsigned short)gc;
      }
    }
  }
  __syncthreads();

  // ====== exact fp32 rescore (bit-identical chain to passing rounds) ======
  {
    const int v = t >> 1, par = t & 1;
    const int gv = bv0 + v;
    const float* xr = X + (size_t)gv * D;
    float rr[8];
#pragma unroll
    for (int j = 0; j < 8; ++j) rr[j] = __fmul_rn(xr[j], xr[j]);
#pragma unroll
    for (int i = 8; i < 64; i += 8)
#pragma unroll
      for (int j = 0; j < 8; ++j)
        rr[j] = __fadd_rn(rr[j], __fmul_rn(xr[i + j], xr[i + j]));
    const float xx = __fadd_rn(
        __fadd_rn(__fadd_rn(rr[0], rr[1]), __fadd_rn(rr[2], rr[3])),
        __fadd_rn(__fadd_rn(rr[4], rr[5]), __fadd_rn(rr[6], rr[7])));

    float best = 3.4e38f;
    int bi = 0x7fffffff;
    const unsigned n = cntL[v];
    if (n <= CAP) {
      for (unsigned i = par; i < n; i += 2) {
        const int c = candL[v * CAP + i];
        const float* er = E + (size_t)c * D;
        float m = 0.f;
#pragma unroll
        for (int j = 0; j < 64; ++j) m = fmaf(er[j], xr[j], m);
        const float dd = __fsub_rn(__fadd_rn(xx, eSqL[c]), 2.0f * m);
        if (dd < best || (dd == best && c < bi)) { best = dd; bi = c; }
      }
    } else {  // overflow fallback: exact full scan (deterministic, correct)
      for (int c = par; c < K; c += 2) {
        const float* er = E + (size_t)c * D;
        float m = 0.f;
#pragma unroll
        for (int j = 0; j < 64; ++j) m = fmaf(er[j], xr[j], m);
        const float dd = __fsub_rn(__fadd_rn(xx, eSqL[c]), 2.0f * m);
        if (dd < best || (dd == best && c < bi)) { best = dd; bi = c; }
      }
    }
    const float ov = __shfl_xor(best, 1, 64);
    const int oi = __shfl_xor(bi, 1, 64);
    if (ov < best || (ov == best && oi < bi)) { best = ov; bi = oi; }
    if (par == 0) sidxL[v] = bi;
  }
  __syncthreads();

  // ============== epilogue: quantized out, indices, loss ==================
  {
    const int v = t >> 1, h = t & 1;
    const int gv = bv0 + v;
    const int code = sidxL[v];
    const f4* er = reinterpret_cast<const f4*>(E + (size_t)code * D + h * 32);
    const f4* xr = reinterpret_cast<const f4*>(X + (size_t)gv * D + h * 32);
    f4* op = reinterpret_cast<f4*>(out + (size_t)gv * D + h * 32);
    float lsum = 0.f;
#pragma unroll
    for (int i = 0; i < 8; ++i) {
      f4 e4 = er[i], x4 = xr[i];
      float d0 = e4[0] - x4[0], d1 = e4[1] - x4[1];
      float d2 = e4[2] - x4[2], d3 = e4[3] - x4[3];
      lsum += d0 * d0 + d1 * d1 + d2 * d2 + d3 * d3;
      op[i] = e4;
    }
    if (t < BM) out[IDX_OFF + bv0 + t] = (float)sidxL[t];
#pragma unroll
    for (int off = 1; off < 64; off <<= 1) lsum += __shfl_xor(lsum, off, 64);
    if (lane == 0)
      atomicAdd(out + LOSS_OFF, lsum * (1.25f / (float)(NV * (size_t)D)));
  }
}

extern "C" void kernel_launch(void* const* d_in, const int* in_sizes, int n_in,
                              void* d_out, int out_size, void* d_ws, size_t ws_size,
                              hipStream_t stream) {
  const float* X = (const float*)d_in[0];
  const float* E = (const float*)d_in[1];
  float* out = (float*)d_out;
  float* ws = (float*)d_ws;  // [0..1024): eSq; then 128 KB swizzled bf16 blob
  vq_prep<<<32, 256, 0, stream>>>(E, ws, out + LOSS_OFF);
  vq_main<<<NV / BM, NT, 0, stream>>>(X, E, ws, out);
}